// Round 10
// baseline (3657.062 us; speedup 1.0000x reference)
//
#include <hip/hip_runtime.h>
#include <cstdint>
#include <cstddef>

// Problem dims (fixed by reference)
#define B_    64
#define T_    4096
#define H_    128
#define C1_   64
#define NCLS_ 40

#define LOG2E_     1.4426950408889634f
#define TWOLOG2E_  2.8853900817779268f
#define NEG4LOG2E_ (-5.7707801635558536f)   // -2 * 2log2e

typedef _Float16 half2_t __attribute__((ext_vector_type(2)));
typedef _Float16 half8_t __attribute__((ext_vector_type(8)));
typedef float    f32x4_t __attribute__((ext_vector_type(4)));

__device__ __forceinline__ half2_t pack2(float a, float b){
  half2_t r; r.x = (_Float16)a; r.y = (_Float16)b; return r;   // RTNE
}

// ---------------- kernel 1: 3x3 second-moment stats of x over B*T ----------------
__global__ __launch_bounds__(256) void stats_kernel(const float* __restrict__ x,
                                                    float* __restrict__ stats){
  int t = blockIdx.x * 256 + threadIdx.x;
  const float4* xv = (const float4*)x + (size_t)t * 3;
  float4 a = xv[0], b = xv[1], c = xv[2];
  float x0[4] = {a.x, a.w, b.z, c.y};
  float x1[4] = {a.y, b.x, b.w, c.z};
  float x2[4] = {a.z, b.y, c.x, c.w};
  float s[9] = {0,0,0,0,0,0,0,0,0};
  #pragma unroll
  for (int r=0;r<4;++r){
    s[0]+=x0[r]; s[1]+=x1[r]; s[2]+=x2[r];
    s[3]+=x0[r]*x0[r]; s[4]+=x0[r]*x1[r]; s[5]+=x0[r]*x2[r];
    s[6]+=x1[r]*x1[r]; s[7]+=x1[r]*x2[r]; s[8]+=x2[r]*x2[r];
  }
  __shared__ float red[9][256];
  #pragma unroll
  for (int j=0;j<9;++j) red[j][threadIdx.x] = s[j];
  __syncthreads();
  if (threadIdx.x < 9){
    float sum = 0.f;
    for (int i=0;i<256;++i) sum += red[threadIdx.x][i];
    atomicAdd(&stats[threadIdx.x], sum);
  }
}

// Fold conv + BN(train stats) + gamma/beta into per-channel affine. conv_b cancels.
__device__ __forceinline__ void chan_affine(int c, const float* __restrict__ conv_w,
    const float* __restrict__ bn_g, const float* __restrict__ bn_b,
    const float* __restrict__ stats,
    float& A0, float& A1, float& A2, float& Bc){
  const float Ninv = 1.0f / (float)(B_*T_);
  float m0=stats[0]*Ninv, m1=stats[1]*Ninv, m2=stats[2]*Ninv;
  float c00=stats[3]*Ninv-m0*m0, c01=stats[4]*Ninv-m0*m1, c02=stats[5]*Ninv-m0*m2;
  float c11=stats[6]*Ninv-m1*m1, c12=stats[7]*Ninv-m1*m2, c22=stats[8]*Ninv-m2*m2;
  float w0=conv_w[c*3+0], w1=conv_w[c*3+1], w2=conv_w[c*3+2];
  float var = w0*(w0*c00 + 2.f*(w1*c01 + w2*c02)) + w1*(w1*c11 + 2.f*w2*c12) + w2*w2*c22;
  float sc = bn_g[c] * rsqrtf(var + 1e-5f);
  A0 = w0*sc; A1 = w1*sc; A2 = w2*sc;
  Bc = bn_b[c] - (w0*m0 + w1*m1 + w2*m2)*sc;
}

// ---------------- fused persistent LSTM, transposed-MFMA recurrence, 2 chains/block ----------------
// 32 blocks x 512 threads (8 waves, 2/SIMD). Each block runs TWO independent batch
// chains (2*blockIdx, 2*blockIdx+1). Rationale: R4's 965-cyc step is ~320 cyc issue
// + ~650 cyc exposed latency (R5/R6/R7/R8 closed the intra-chain axes). A second
// INDEPENDENT chain's instructions fill the first chain's stall windows, and the
// stationary weights (Wf/bf/sgb) are batch-shared — so chain 2 costs only extra
// state registers (cs/xp/pq/h-frags), not a second weight set. Same barrier count.
//
// Per chain, per 16-step chunk: blob MFMAs P[s][n] = sg*(W_ih.relu(affine(x)) +
// b_ih + b_hh) into P_lds[ch] (row s, dword col (n&127)*4+gate, stride 516 dw).
// Recurrence per step, per chain, TRANSPOSED MFMA: D = A(h-bcast) x B(W_hh^T).
//   A-frag: h[kc*32+kgrp*8+j] (rows replicated); B-frag: stationary Wf.
//   4 chained MFMAs per gate (R7 showed splitting hurts). Lane owns element
//   wv*16+rfrag, all 4 gates in-lane; kgrp==0 writes h. Tail per chain in-lane.
// cs carried scaled by 2log2e. One barrier per step, lgkmcnt-only drain. pq
// prefetched 1 step ahead; chunk-boundary WAR safe (chunk P reads drain at the
// step-15 barrier). All chain indexing via #pragma unroll ch -> static (rule #20).
__global__ __launch_bounds__(512,2) void lstm_fused_kernel(
    const float* __restrict__ x,
    const float* __restrict__ conv_w, const float* __restrict__ bn_g,
    const float* __restrict__ bn_b, const float* __restrict__ stats,
    const float* __restrict__ w_ih, const float* __restrict__ b_ih,
    const float* __restrict__ b_hh, const float* __restrict__ w_hh,
    const float* __restrict__ h0, const float* __restrict__ c0,
    const float* __restrict__ out_w, const float* __restrict__ out_b,
    float* __restrict__ out){
  constexpr int CH   = 16;    // steps per chunk
  constexpr int PSTR = 516;   // P row stride in dwords: 516*4 = 2064 B, 16B aligned
  int bb = blockIdx.x * 2, t = threadIdx.x;
  int lane = t & 63, wv = t >> 6;
  int rfrag = lane & 15, kgrp = lane >> 4;
  int estar = wv*16 + rfrag;                      // this lane's h element (both chains)
  bool wrt = (kgrp == 0);

  __shared__ __align__(16) _Float16 hbuf[2][2][H_];   // [chain][parity][elem]
  __shared__ __align__(16) float P_lds[2][CH * PSTR]; // [chain] — 66 KB total
  __shared__ __align__(16) float4 cf_lds[C1_];

  if (t < C1_){
    float A0,A1,A2,Bc; chan_affine(t, conv_w, bn_g, bn_b, stats, A0,A1,A2,Bc);
    cf_lds[t] = make_float4(A0,A1,A2,Bc);
  }

  // ---- stationary recurrent weights as B-frags: Wf[g][kc], sg folded (batch-shared) ----
  half8_t Wf[4][4];
  #pragma unroll
  for (int g=0; g<4; ++g){
    float sg = (g==2) ? TWOLOG2E_ : -LOG2E_;
    #pragma unroll
    for (int kc=0; kc<4; ++kc){
      const float4* wp = (const float4*)(w_hh + (size_t)(g*H_ + wv*16 + rfrag)*H_ + kc*32 + kgrp*8);
      float4 u0 = wp[0], u1 = wp[1];
      half8_t hv;
      hv[0]=(_Float16)(sg*u0.x); hv[1]=(_Float16)(sg*u0.y);
      hv[2]=(_Float16)(sg*u0.z); hv[3]=(_Float16)(sg*u0.w);
      hv[4]=(_Float16)(sg*u1.x); hv[5]=(_Float16)(sg*u1.y);
      hv[6]=(_Float16)(sg*u1.z); hv[7]=(_Float16)(sg*u1.w);
      Wf[g][kc] = hv;
    }
  }
  // ---- producer B-frags (W_ih) + folded biases (batch-shared) ----
  half8_t bf[4][2];
  float sgb[4];
  #pragma unroll
  for (int g=0; g<4; ++g){
    int n = g*H_ + wv*16 + rfrag;
    float sg = (g==2) ? TWOLOG2E_ : -LOG2E_;
    sgb[g] = sg * (b_ih[n] + b_hh[n]);
    #pragma unroll
    for (int kh=0; kh<2; ++kh){
      const float4* wp = (const float4*)(w_ih + (size_t)n*C1_ + kh*32 + kgrp*8);
      float4 u0 = wp[0], u1 = wp[1];
      half8_t hv;
      hv[0]=(_Float16)(sg*u0.x); hv[1]=(_Float16)(sg*u0.y);
      hv[2]=(_Float16)(sg*u0.z); hv[3]=(_Float16)(sg*u0.w);
      hv[4]=(_Float16)(sg*u1.x); hv[5]=(_Float16)(sg*u1.y);
      hv[6]=(_Float16)(sg*u1.z); hv[7]=(_Float16)(sg*u1.w);
      bf[g][kh] = hv;
    }
  }

  // ---- per-chain state ----
  float cs[2];
  float xp[2][3];
  #pragma unroll
  for (int ch=0; ch<2; ++ch){
    cs[ch] = TWOLOG2E_ * c0[(size_t)(bb+ch)*H_ + estar];   // scaled cell (kgrp-redundant)
    if (wrt) hbuf[ch][0][estar] = (_Float16)h0[(size_t)(bb+ch)*H_ + estar];
    const float* p = x + ((size_t)(bb+ch)*T_ + rfrag)*3;   // chunk-0 x (A-row = rfrag)
    xp[ch][0] = p[0]; xp[ch][1] = p[1]; xp[ch][2] = p[2];
  }
  const f32x4_t Z = {0.f, 0.f, 0.f, 0.f};            // hoisted MFMA C-init
  __syncthreads();

  for (int c = 0; c < T_/CH; ++c){
    // ===== blob: P tiles for steps [c*16, c*16+16), both chains =====
    #pragma unroll
    for (int ch=0; ch<2; ++ch){
      half8_t a0, a1;
      #pragma unroll
      for (int j=0;j<8;++j){
        float4 q = cf_lds[kgrp*8+j];
        a0[j] = (_Float16)fmaxf(fmaf(q.x,xp[ch][0], fmaf(q.y,xp[ch][1], fmaf(q.z,xp[ch][2], q.w))), 0.f);
        float4 rr = cf_lds[32+kgrp*8+j];
        a1[j] = (_Float16)fmaxf(fmaf(rr.x,xp[ch][0], fmaf(rr.y,xp[ch][1], fmaf(rr.z,xp[ch][2], rr.w))), 0.f);
      }
      { int row = (c+1)*CH + rfrag; row = (row < T_) ? row : (T_-1);
        const float* p = x + ((size_t)(bb+ch)*T_ + row)*3;
        xp[ch][0] = p[0]; xp[ch][1] = p[1]; xp[ch][2] = p[2]; }
      #pragma unroll
      for (int g=0; g<4; ++g){
        f32x4_t dp = __builtin_amdgcn_mfma_f32_16x16x32_f16(a0, bf[g][0], Z, 0, 0, 0);
        dp = __builtin_amdgcn_mfma_f32_16x16x32_f16(a1, bf[g][1], dp, 0, 0, 0);
        int col = (wv*16 + rfrag)*4 + g;             // element-major, gate-minor
        #pragma unroll
        for (int v4=0; v4<4; ++v4)
          P_lds[ch][(kgrp*4 + v4)*PSTR + col] = dp[v4] + sgb[g];
      }
    }
    asm volatile("s_waitcnt lgkmcnt(0)" ::: "memory");
    __builtin_amdgcn_s_barrier();                  // serves as step-0 barrier too
    asm volatile("" ::: "memory");

    // pq for step 0: lane's element, 4 gates, one b128 per chain
    f32x4_t pq[2];
    pq[0] = *(const f32x4_t*)(P_lds[0] + (size_t)estar*4);
    pq[1] = *(const f32x4_t*)(P_lds[1] + (size_t)estar*4);

    // ===== 16 recurrence steps, both chains interleaved between barriers =====
    #pragma unroll
    for (int s=0; s<CH; ++s){
      int p = s & 1;                               // c*16 even -> parity == s&1
      if (s > 0){
        asm volatile("s_waitcnt lgkmcnt(0)" ::: "memory");
        __builtin_amdgcn_s_barrier();
        asm volatile("" ::: "memory");
      }
      // h broadcast reads, both chains (independent dataflow)
      uint4 hu[2][4];
      #pragma unroll
      for (int ch=0; ch<2; ++ch){
        const _Float16* hb = hbuf[ch][p];
        hu[ch][0] = *(const uint4*)(hb + 0*32 + kgrp*8);
        hu[ch][1] = *(const uint4*)(hb + 1*32 + kgrp*8);
        hu[ch][2] = *(const uint4*)(hb + 2*32 + kgrp*8);
        hu[ch][3] = *(const uint4*)(hb + 3*32 + kgrp*8);
      }
      f32x4_t pqn[2] = {pq[0], pq[1]};
      if (s < CH-1){
        pqn[0] = *(const f32x4_t*)(P_lds[0] + (size_t)(s+1)*PSTR + estar*4);
        pqn[1] = *(const f32x4_t*)(P_lds[1] + (size_t)(s+1)*PSTR + estar*4);
      }
      #pragma unroll
      for (int ch=0; ch<2; ++ch){
        half8_t A0 = __builtin_bit_cast(half8_t, hu[ch][0]);
        half8_t A1 = __builtin_bit_cast(half8_t, hu[ch][1]);
        half8_t A2 = __builtin_bit_cast(half8_t, hu[ch][2]);
        half8_t A3 = __builtin_bit_cast(half8_t, hu[ch][3]);
        // 4 independent 4-deep chains on the matrix pipe (per chain)
        f32x4_t d0 = __builtin_amdgcn_mfma_f32_16x16x32_f16(A0, Wf[0][0], Z, 0,0,0);
        f32x4_t d1 = __builtin_amdgcn_mfma_f32_16x16x32_f16(A0, Wf[1][0], Z, 0,0,0);
        f32x4_t d2 = __builtin_amdgcn_mfma_f32_16x16x32_f16(A0, Wf[2][0], Z, 0,0,0);
        f32x4_t d3 = __builtin_amdgcn_mfma_f32_16x16x32_f16(A0, Wf[3][0], Z, 0,0,0);
        d0 = __builtin_amdgcn_mfma_f32_16x16x32_f16(A1, Wf[0][1], d0, 0,0,0);
        d1 = __builtin_amdgcn_mfma_f32_16x16x32_f16(A1, Wf[1][1], d1, 0,0,0);
        d2 = __builtin_amdgcn_mfma_f32_16x16x32_f16(A1, Wf[2][1], d2, 0,0,0);
        d3 = __builtin_amdgcn_mfma_f32_16x16x32_f16(A1, Wf[3][1], d3, 0,0,0);
        d0 = __builtin_amdgcn_mfma_f32_16x16x32_f16(A2, Wf[0][2], d0, 0,0,0);
        d1 = __builtin_amdgcn_mfma_f32_16x16x32_f16(A2, Wf[1][2], d1, 0,0,0);
        d2 = __builtin_amdgcn_mfma_f32_16x16x32_f16(A2, Wf[2][2], d2, 0,0,0);
        d3 = __builtin_amdgcn_mfma_f32_16x16x32_f16(A2, Wf[3][2], d3, 0,0,0);
        d0 = __builtin_amdgcn_mfma_f32_16x16x32_f16(A3, Wf[0][3], d0, 0,0,0);
        d1 = __builtin_amdgcn_mfma_f32_16x16x32_f16(A3, Wf[1][3], d1, 0,0,0);
        d2 = __builtin_amdgcn_mfma_f32_16x16x32_f16(A3, Wf[2][3], d2, 0,0,0);
        d3 = __builtin_amdgcn_mfma_f32_16x16x32_f16(A3, Wf[3][3], d3, 0,0,0);
        // component 0 == lane's element (rows replicated) — no picks
        float vI = d0[0] + pq[ch][0];
        float vF = d1[0] + pq[ch][1];
        float vG = d2[0] + pq[ch][2];
        float vO = d3[0] + pq[ch][3];
        float rI = __builtin_amdgcn_rcpf(1.f + __builtin_amdgcn_exp2f(vI));  // sigmoid(i)
        float rF = __builtin_amdgcn_rcpf(1.f + __builtin_amdgcn_exp2f(vF));  // sigmoid(f)
        float rG = __builtin_amdgcn_rcpf(1.f + __builtin_amdgcn_exp2f(vG));  // -> tanh(g)
        float rO = __builtin_amdgcn_rcpf(1.f + __builtin_amdgcn_exp2f(vO));  // sigmoid(o)
        float gT2 = fmaf(NEG4LOG2E_, rG, TWOLOG2E_);   // 2log2e * tanh(g)
        float cn  = fmaf(rF, cs[ch], rI * gT2);        // scaled c'
        cs[ch] = cn;
        float th = fmaf(-2.f, __builtin_amdgcn_rcpf(1.f + __builtin_amdgcn_exp2f(cn)), 1.f);
        float h  = rO * th;
        if (wrt) hbuf[ch][1-p][estar] = (_Float16)h;
        pq[ch] = pqn[ch];
      }
    }
  }
  __syncthreads();
  // classifier epilogue on final h (T even -> parity 0), both chains
  if (t < NCLS_){
    #pragma unroll
    for (int ch=0; ch<2; ++ch){
      float s = out_b[t];
      #pragma unroll 8
      for (int kk=0; kk<H_; ++kk)
        s = fmaf(out_w[t*H_ + kk], (float)hbuf[ch][0][kk], s);
      out[(size_t)(bb+ch)*NCLS_ + t] = s;
    }
  }
}

extern "C" void kernel_launch(void* const* d_in, const int* in_sizes, int n_in,
                              void* d_out, int out_size, void* d_ws, size_t ws_size,
                              hipStream_t stream){
  const float* x      = (const float*)d_in[0];
  const float* conv_w = (const float*)d_in[1];
  // d_in[2] = conv_b: cancels exactly inside BN(train stats) — unused
  const float* bn_g   = (const float*)d_in[3];
  const float* bn_b   = (const float*)d_in[4];
  const float* w_ih   = (const float*)d_in[5];
  const float* b_ih   = (const float*)d_in[6];
  const float* w_hh   = (const float*)d_in[7];
  const float* b_hh   = (const float*)d_in[8];
  const float* out_w  = (const float*)d_in[9];
  const float* out_b  = (const float*)d_in[10];
  const float* h0     = (const float*)d_in[11];
  const float* c0     = (const float*)d_in[12];
  float* out   = (float*)d_out;
  float* stats = (float*)d_ws;

  hipMemsetAsync(d_ws, 0, 64, stream);
  stats_kernel<<<256, 256, 0, stream>>>(x, stats);
  lstm_fused_kernel<<<B_/2, 512, 0, stream>>>(x, conv_w, bn_g, bn_b, stats,
                                              w_ih, b_ih, b_hh, w_hh, h0, c0,
                                              out_w, out_b, out);
}

// Round 11
// 1684.567 us; speedup vs baseline: 2.1709x; 2.1709x over previous
//
#include <hip/hip_runtime.h>
#include <cstdint>
#include <cstddef>

// Problem dims (fixed by reference)
#define B_    64
#define T_    4096
#define H_    128
#define C1_   64
#define NCLS_ 40

#define LOG2E_     1.4426950408889634f
#define TWOLOG2E_  2.8853900817779268f
#define NEG4LOG2E_ (-5.7707801635558536f)   // -2 * 2log2e

typedef _Float16 half2_t __attribute__((ext_vector_type(2)));
typedef _Float16 half8_t __attribute__((ext_vector_type(8)));
typedef float    f32x4_t __attribute__((ext_vector_type(4)));

__device__ __forceinline__ half2_t pack2(float a, float b){
  half2_t r; r.x = (_Float16)a; r.y = (_Float16)b; return r;   // RTNE
}

// ---------------- kernel 1: 3x3 second-moment stats of x over B*T ----------------
__global__ __launch_bounds__(256) void stats_kernel(const float* __restrict__ x,
                                                    float* __restrict__ stats){
  int t = blockIdx.x * 256 + threadIdx.x;
  const float4* xv = (const float4*)x + (size_t)t * 3;
  float4 a = xv[0], b = xv[1], c = xv[2];
  float x0[4] = {a.x, a.w, b.z, c.y};
  float x1[4] = {a.y, b.x, b.w, c.z};
  float x2[4] = {a.z, b.y, c.x, c.w};
  float s[9] = {0,0,0,0,0,0,0,0,0};
  #pragma unroll
  for (int r=0;r<4;++r){
    s[0]+=x0[r]; s[1]+=x1[r]; s[2]+=x2[r];
    s[3]+=x0[r]*x0[r]; s[4]+=x0[r]*x1[r]; s[5]+=x0[r]*x2[r];
    s[6]+=x1[r]*x1[r]; s[7]+=x1[r]*x2[r]; s[8]+=x2[r]*x2[r];
  }
  __shared__ float red[9][256];
  #pragma unroll
  for (int j=0;j<9;++j) red[j][threadIdx.x] = s[j];
  __syncthreads();
  if (threadIdx.x < 9){
    float sum = 0.f;
    for (int i=0;i<256;++i) sum += red[threadIdx.x][i];
    atomicAdd(&stats[threadIdx.x], sum);
  }
}

// Fold conv + BN(train stats) + gamma/beta into per-channel affine. conv_b cancels.
__device__ __forceinline__ void chan_affine(int c, const float* __restrict__ conv_w,
    const float* __restrict__ bn_g, const float* __restrict__ bn_b,
    const float* __restrict__ stats,
    float& A0, float& A1, float& A2, float& Bc){
  const float Ninv = 1.0f / (float)(B_*T_);
  float m0=stats[0]*Ninv, m1=stats[1]*Ninv, m2=stats[2]*Ninv;
  float c00=stats[3]*Ninv-m0*m0, c01=stats[4]*Ninv-m0*m1, c02=stats[5]*Ninv-m0*m2;
  float c11=stats[6]*Ninv-m1*m1, c12=stats[7]*Ninv-m1*m2, c22=stats[8]*Ninv-m2*m2;
  float w0=conv_w[c*3+0], w1=conv_w[c*3+1], w2=conv_w[c*3+2];
  float var = w0*(w0*c00 + 2.f*(w1*c01 + w2*c02)) + w1*(w1*c11 + 2.f*w2*c12) + w2*w2*c22;
  float sc = bn_g[c] * rsqrtf(var + 1e-5f);
  A0 = w0*sc; A1 = w1*sc; A2 = w2*sc;
  Bc = bn_b[c] - (w0*m0 + w1*m1 + w2*m2)*sc;
}

// ---------------- fused persistent LSTM, transposed-MFMA recurrence ----------------
// R4/R9 structure verbatim — best measured (1660 us dispatch, 965 cyc/step).
// 64 blocks x 512 threads (8 waves, 2/SIMD). Experiment matrix CLOSED:
//   R5 1/SIMD (+11%), R6 DPP redistribution (+34%), R7 split chains (+21%),
//   R8 persistent setprio (crash), R10 2 chains/block (+117% — barrier-shared
//   stalls; LDS instrs x2; 8.4M bank conflicts).
// The chained, 4-read, one-barrier-per-step form is the floor of this structure.
// Remaining step cost is the inherent serial recurrence path (barrier + LDS
// round-trip + MFMA chain + serial activation tail), not a pipe bottleneck
// (MfmaUtil 13.8 / VALUBusy 12 / HBM 0.03% chip-wide — latency-bound, not
// throughput-bound).
//
// Blob per 16-step chunk: P[s][n] = sg*(W_ih.relu(affine(x)) + b_ih + b_hh) -> LDS
// (row s, dword col (n&127)*4 + gate, stride 516 dw).
// Recurrence per step on the MATRIX pipe, TRANSPOSED: D = A(h-bcast) x B(W_hh^T).
//   A-frag: A[r][k] = h[kc*32 + kgrp*8 + j] — row-independent -> all D rows equal.
//   B-frag: B[k][n] = sg*w_hh[g*128 + wv*16 + rfrag][kc*32 + kgrp*8 + j], stationary.
//   4 independent 4-deep MFMA chains (one per gate); D[r][c] rows replicated ->
//   lane reads [0]; lane owns element wv*16+rfrag, all 4 gates in-lane (kgrp 4x
//   redundant; kgrp==0 writes h).
// cs carried scaled by 2log2e. One barrier per step, lgkmcnt-only drain. pq (lane's
// element's 4 gates) one b128, prefetched 1 step ahead; chunk-boundary WAR safe
// (all chunk P reads drain at the step-15 barrier).
__global__ __launch_bounds__(512,2) void lstm_fused_kernel(
    const float* __restrict__ x,
    const float* __restrict__ conv_w, const float* __restrict__ bn_g,
    const float* __restrict__ bn_b, const float* __restrict__ stats,
    const float* __restrict__ w_ih, const float* __restrict__ b_ih,
    const float* __restrict__ b_hh, const float* __restrict__ w_hh,
    const float* __restrict__ h0, const float* __restrict__ c0,
    const float* __restrict__ out_w, const float* __restrict__ out_b,
    float* __restrict__ out){
  constexpr int CH   = 16;    // steps per chunk
  constexpr int PSTR = 516;   // P row stride in dwords: 516*4 = 2064 B, 16B aligned
  int b = blockIdx.x, t = threadIdx.x;
  int lane = t & 63, wv = t >> 6;
  int rfrag = lane & 15, kgrp = lane >> 4;
  int estar = wv*16 + rfrag;                      // this lane's h element
  bool wrt = (kgrp == 0);

  __shared__ __align__(16) _Float16 hbuf[2][H_];
  __shared__ __align__(16) float P_lds[CH * PSTR];
  __shared__ __align__(16) float4 cf_lds[C1_];

  if (t < C1_){
    float A0,A1,A2,Bc; chan_affine(t, conv_w, bn_g, bn_b, stats, A0,A1,A2,Bc);
    cf_lds[t] = make_float4(A0,A1,A2,Bc);
  }

  // ---- stationary recurrent weights as B-frags: Wf[g][kc], sg prescale folded ----
  half8_t Wf[4][4];
  #pragma unroll
  for (int g=0; g<4; ++g){
    float sg = (g==2) ? TWOLOG2E_ : -LOG2E_;
    #pragma unroll
    for (int kc=0; kc<4; ++kc){
      const float4* wp = (const float4*)(w_hh + (size_t)(g*H_ + wv*16 + rfrag)*H_ + kc*32 + kgrp*8);
      float4 u0 = wp[0], u1 = wp[1];
      half8_t hv;
      hv[0]=(_Float16)(sg*u0.x); hv[1]=(_Float16)(sg*u0.y);
      hv[2]=(_Float16)(sg*u0.z); hv[3]=(_Float16)(sg*u0.w);
      hv[4]=(_Float16)(sg*u1.x); hv[5]=(_Float16)(sg*u1.y);
      hv[6]=(_Float16)(sg*u1.z); hv[7]=(_Float16)(sg*u1.w);
      Wf[g][kc] = hv;
    }
  }
  // ---- producer B-frags (W_ih) + folded biases: wave wv owns n = g*128+wv*16+rfrag ----
  half8_t bf[4][2];
  float sgb[4];
  #pragma unroll
  for (int g=0; g<4; ++g){
    int n = g*H_ + wv*16 + rfrag;
    float sg = (g==2) ? TWOLOG2E_ : -LOG2E_;
    sgb[g] = sg * (b_ih[n] + b_hh[n]);
    #pragma unroll
    for (int kh=0; kh<2; ++kh){
      const float4* wp = (const float4*)(w_ih + (size_t)n*C1_ + kh*32 + kgrp*8);
      float4 u0 = wp[0], u1 = wp[1];
      half8_t hv;
      hv[0]=(_Float16)(sg*u0.x); hv[1]=(_Float16)(sg*u0.y);
      hv[2]=(_Float16)(sg*u0.z); hv[3]=(_Float16)(sg*u0.w);
      hv[4]=(_Float16)(sg*u1.x); hv[5]=(_Float16)(sg*u1.y);
      hv[6]=(_Float16)(sg*u1.z); hv[7]=(_Float16)(sg*u1.w);
      bf[g][kh] = hv;
    }
  }

  float cs = TWOLOG2E_ * c0[(size_t)b*H_ + estar];   // scaled cell state (kgrp-redundant)
  if (wrt) hbuf[0][estar] = (_Float16)h0[(size_t)b*H_ + estar];

  // ---- x prefetch for chunk 0 (producer A-row = timestep rfrag) ----
  const float* xb = x + (size_t)b*T_*3;
  float xp0, xp1, xp2;
  { const float* p = xb + 3*rfrag; xp0 = p[0]; xp1 = p[1]; xp2 = p[2]; }
  const f32x4_t Z = {0.f, 0.f, 0.f, 0.f};            // hoisted MFMA C-init
  __syncthreads();

  for (int c = 0; c < T_/CH; ++c){
    // ===== blob: P tile for steps [c*16, c*16+16) =====
    half8_t a0, a1;
    #pragma unroll
    for (int j=0;j<8;++j){
      float4 q = cf_lds[kgrp*8+j];
      a0[j] = (_Float16)fmaxf(fmaf(q.x,xp0, fmaf(q.y,xp1, fmaf(q.z,xp2, q.w))), 0.f);
      float4 rr = cf_lds[32+kgrp*8+j];
      a1[j] = (_Float16)fmaxf(fmaf(rr.x,xp0, fmaf(rr.y,xp1, fmaf(rr.z,xp2, rr.w))), 0.f);
    }
    { int row = (c+1)*CH + rfrag; row = (row < T_) ? row : (T_-1);
      const float* p = xb + 3*row; xp0 = p[0]; xp1 = p[1]; xp2 = p[2]; }
    #pragma unroll
    for (int g=0; g<4; ++g){
      f32x4_t dp = __builtin_amdgcn_mfma_f32_16x16x32_f16(a0, bf[g][0], Z, 0, 0, 0);
      dp = __builtin_amdgcn_mfma_f32_16x16x32_f16(a1, bf[g][1], dp, 0, 0, 0);
      int col = (wv*16 + rfrag)*4 + g;             // element-major, gate-minor
      #pragma unroll
      for (int v4=0; v4<4; ++v4)
        P_lds[(kgrp*4 + v4)*PSTR + col] = dp[v4] + sgb[g];
    }
    asm volatile("s_waitcnt lgkmcnt(0)" ::: "memory");
    __builtin_amdgcn_s_barrier();                  // serves as step-0 barrier too
    asm volatile("" ::: "memory");

    // pq for step 0: lane's element, 4 gates, one b128
    f32x4_t pq = *(const f32x4_t*)(P_lds + (size_t)estar*4);

    // ===== 16 recurrence steps =====
    #pragma unroll
    for (int s=0; s<CH; ++s){
      int p = s & 1;                               // c*16 even -> parity == s&1
      if (s > 0){
        asm volatile("s_waitcnt lgkmcnt(0)" ::: "memory");
        __builtin_amdgcn_s_barrier();
        asm volatile("" ::: "memory");
      }
      const _Float16* hb = hbuf[p];
      // A-frags: h broadcast (16-lane same-address reads, conflict-free)
      uint4 hu0 = *(const uint4*)(hb + 0*32 + kgrp*8);
      uint4 hu1 = *(const uint4*)(hb + 1*32 + kgrp*8);
      uint4 hu2 = *(const uint4*)(hb + 2*32 + kgrp*8);
      uint4 hu3 = *(const uint4*)(hb + 3*32 + kgrp*8);
      f32x4_t pqn = pq;
      if (s < CH-1) pqn = *(const f32x4_t*)(P_lds + (size_t)(s+1)*PSTR + estar*4);
      half8_t A0 = __builtin_bit_cast(half8_t, hu0);
      half8_t A1 = __builtin_bit_cast(half8_t, hu1);
      half8_t A2 = __builtin_bit_cast(half8_t, hu2);
      half8_t A3 = __builtin_bit_cast(half8_t, hu3);
      // 4 independent 4-deep chains on the matrix pipe; C-init from hoisted Z
      f32x4_t d0 = __builtin_amdgcn_mfma_f32_16x16x32_f16(A0, Wf[0][0], Z, 0,0,0);
      f32x4_t d1 = __builtin_amdgcn_mfma_f32_16x16x32_f16(A0, Wf[1][0], Z, 0,0,0);
      f32x4_t d2 = __builtin_amdgcn_mfma_f32_16x16x32_f16(A0, Wf[2][0], Z, 0,0,0);
      f32x4_t d3 = __builtin_amdgcn_mfma_f32_16x16x32_f16(A0, Wf[3][0], Z, 0,0,0);
      d0 = __builtin_amdgcn_mfma_f32_16x16x32_f16(A1, Wf[0][1], d0, 0,0,0);
      d1 = __builtin_amdgcn_mfma_f32_16x16x32_f16(A1, Wf[1][1], d1, 0,0,0);
      d2 = __builtin_amdgcn_mfma_f32_16x16x32_f16(A1, Wf[2][1], d2, 0,0,0);
      d3 = __builtin_amdgcn_mfma_f32_16x16x32_f16(A1, Wf[3][1], d3, 0,0,0);
      d0 = __builtin_amdgcn_mfma_f32_16x16x32_f16(A2, Wf[0][2], d0, 0,0,0);
      d1 = __builtin_amdgcn_mfma_f32_16x16x32_f16(A2, Wf[1][2], d1, 0,0,0);
      d2 = __builtin_amdgcn_mfma_f32_16x16x32_f16(A2, Wf[2][2], d2, 0,0,0);
      d3 = __builtin_amdgcn_mfma_f32_16x16x32_f16(A2, Wf[3][2], d3, 0,0,0);
      d0 = __builtin_amdgcn_mfma_f32_16x16x32_f16(A3, Wf[0][3], d0, 0,0,0);
      d1 = __builtin_amdgcn_mfma_f32_16x16x32_f16(A3, Wf[1][3], d1, 0,0,0);
      d2 = __builtin_amdgcn_mfma_f32_16x16x32_f16(A3, Wf[2][3], d2, 0,0,0);
      d3 = __builtin_amdgcn_mfma_f32_16x16x32_f16(A3, Wf[3][3], d3, 0,0,0);
      // component 0 == lane's element (rows replicated) — no picks
      float vI = d0[0] + pq[0];
      float vF = d1[0] + pq[1];
      float vG = d2[0] + pq[2];
      float vO = d3[0] + pq[3];
      float rI = __builtin_amdgcn_rcpf(1.f + __builtin_amdgcn_exp2f(vI));  // sigmoid(i)
      float rF = __builtin_amdgcn_rcpf(1.f + __builtin_amdgcn_exp2f(vF));  // sigmoid(f)
      float rG = __builtin_amdgcn_rcpf(1.f + __builtin_amdgcn_exp2f(vG));  // -> tanh(g)
      float rO = __builtin_amdgcn_rcpf(1.f + __builtin_amdgcn_exp2f(vO));  // sigmoid(o)
      float gT2 = fmaf(NEG4LOG2E_, rG, TWOLOG2E_);   // 2log2e * tanh(g)
      float cn  = fmaf(rF, cs, rI * gT2);            // scaled c'
      cs = cn;
      float th = fmaf(-2.f, __builtin_amdgcn_rcpf(1.f + __builtin_amdgcn_exp2f(cn)), 1.f);
      float h  = rO * th;
      if (wrt) hbuf[1-p][estar] = (_Float16)h;
      pq = pqn;
    }
  }
  __syncthreads();
  // classifier epilogue on final h (T even -> buffer 0)
  if (t < NCLS_){
    float s = out_b[t];
    #pragma unroll 8
    for (int kk=0; kk<H_; ++kk)
      s = fmaf(out_w[t*H_ + kk], (float)hbuf[0][kk], s);
    out[(size_t)b*NCLS_ + t] = s;
  }
}

extern "C" void kernel_launch(void* const* d_in, const int* in_sizes, int n_in,
                              void* d_out, int out_size, void* d_ws, size_t ws_size,
                              hipStream_t stream){
  const float* x      = (const float*)d_in[0];
  const float* conv_w = (const float*)d_in[1];
  // d_in[2] = conv_b: cancels exactly inside BN(train stats) — unused
  const float* bn_g   = (const float*)d_in[3];
  const float* bn_b   = (const float*)d_in[4];
  const float* w_ih   = (const float*)d_in[5];
  const float* b_ih   = (const float*)d_in[6];
  const float* w_hh   = (const float*)d_in[7];
  const float* b_hh   = (const float*)d_in[8];
  const float* out_w  = (const float*)d_in[9];
  const float* out_b  = (const float*)d_in[10];
  const float* h0     = (const float*)d_in[11];
  const float* c0     = (const float*)d_in[12];
  float* out   = (float*)d_out;
  float* stats = (float*)d_ws;

  hipMemsetAsync(d_ws, 0, 64, stream);
  stats_kernel<<<256, 256, 0, stream>>>(x, stats);
  lstm_fused_kernel<<<B_, 512, 0, stream>>>(x, conv_w, bn_g, bn_b, stats,
                                            w_ih, b_ih, b_hh, w_hh, h0, c0,
                                            out_w, out_b, out);
}